// Round 12
// baseline (286.395 us; speedup 1.0000x reference)
//
#include <hip/hip_runtime.h>
#include <hip/hip_bf16.h>
#include <math.h>

typedef __bf16 bf16;
typedef __attribute__((ext_vector_type(8))) __bf16 bf16x8;
typedef __attribute__((ext_vector_type(4))) __bf16 bf16x4;
typedef __attribute__((ext_vector_type(4))) float f32x4;

#define EPSBN 1e-5f
#define B_    4096
#define N_    64
#define FIN_  67
#define E_    512
#define NSLOT 128

__device__ inline bf16x8 pack8(f32x4 lo, f32x4 hi) {
    bf16x8 r;
    r[0] = (bf16)lo[0]; r[1] = (bf16)lo[1]; r[2] = (bf16)lo[2]; r[3] = (bf16)lo[3];
    r[4] = (bf16)hi[0]; r[5] = (bf16)hi[1]; r[6] = (bf16)hi[2]; r[7] = (bf16)hi[3];
    return r;
}

// ---------------- K0: adjacency + padded weights + Wl1->bf16 prepack + zero partials ----------
// blocks 0:An  1:wpad  2:w2pad  3..63: wl1b = bf16(Wl1) padded to [448][2048] (rows>=400 zero)
__global__ __launch_bounds__(256) void k0_prep(const int* __restrict__ edge,
    const float* __restrict__ W1, const float* __restrict__ W2,
    const float* __restrict__ Wl1,
    float* __restrict__ partials,
    bf16* __restrict__ an_hi, bf16* __restrict__ an_lo,
    bf16* __restrict__ wpad,               // [64][104] bf16
    bf16* __restrict__ w2pad,              // [32][72]  bf16
    bf16* __restrict__ wl1b)               // [448][2048] bf16
{
    int tid = threadIdx.x;
    for (int i = blockIdx.x * 256 + tid; i < NSLOT * 64 * 4; i += gridDim.x * 256)
        partials[i] = 0.f;
    if (blockIdx.x == 1) {
        for (int i = tid; i < 64 * 104; i += 256) {
            int n = i / 104, f = i % 104;
            wpad[i] = (f < FIN_) ? (bf16)W1[n * FIN_ + f] : (bf16)0.f;
        }
        return;
    }
    if (blockIdx.x == 2) {
        for (int i = tid; i < 32 * 72; i += 256) {
            int o = i / 72, f = i % 72;
            w2pad[i] = (f < 64) ? (bf16)W2[o * 64 + f] : (bf16)0.f;
        }
        return;
    }
    if (blockIdx.x >= 3) {                            // 61 blocks: Wl1 -> bf16 [448][2048]
        for (int i = (blockIdx.x - 3) * 256 + tid; i < 448 * 256; i += 61 * 256) {
            int row = i >> 8, col = (i & 255) * 8;    // 256 bf16x8 chunks per row
            bf16x8 o;
            if (row < 400) {
                const float* p = Wl1 + (size_t)row * 2048 + col;
                o = pack8(*(const f32x4*)p, *(const f32x4*)(p + 4));
            } else {
#pragma unroll
                for (int k = 0; k < 8; ++k) o[k] = (bf16)0.f;
            }
            *(bf16x8*)&wl1b[(size_t)row * 2048 + col] = o;
        }
        return;
    }

    __shared__ float An[64 * 64];
    __shared__ int ssrc[E_], sdst[E_];
    __shared__ int deg[N_];
    __shared__ float dinv[N_];
    for (int i = tid; i < 64 * 64; i += 256) An[i] = 0.f;
    for (int i = tid; i < E_; i += 256) { ssrc[i] = edge[i]; sdst[i] = edge[E_ + i]; }
    if (tid < N_) deg[tid] = 1;                       // self loop contributes 1
    __syncthreads();
    for (int i = tid; i < E_; i += 256) atomicAdd(&deg[sdst[i]], 1);
    __syncthreads();
    if (tid < N_) dinv[tid] = rsqrtf((float)deg[tid]);
    __syncthreads();
    for (int i = tid; i < E_; i += 256) {
        int s = ssrc[i], d = sdst[i];
        atomicAdd(&An[d * 64 + s], dinv[s] * dinv[d]);
    }
    if (tid < N_) atomicAdd(&An[tid * 64 + tid], dinv[tid] * dinv[tid]);
    __syncthreads();
    for (int i = tid; i < 64 * 64; i += 256) {
        float v = An[i];
        bf16 h = (bf16)v;
        an_hi[i] = h;
        an_lo[i] = (bf16)(v - (float)h);
    }
}

// ---------------- K1: GCN layer 1, 4 batches/block, reg-prefetch pipelined ----------------
__global__ __launch_bounds__(256, 3) void k1_gcn1(
    const float* __restrict__ x,          // [B][64][67]
    const float* __restrict__ b1,
    const bf16* __restrict__ an_hi, const bf16* __restrict__ an_lo,
    const bf16* __restrict__ wpad,        // [64][104] bf16
    bf16* __restrict__ g1out,             // [B][64][64]
    float* __restrict__ part1)            // [NSLOT][64][2]
{
    __shared__ union {
        float xraw[4352];
        struct { bf16 hhi[64 * 72]; bf16 hlo[64 * 72]; } h;
    } u;
    __shared__ bf16 ost[64 * 72];

    int tid = threadIdx.x;
    int w = tid >> 6, lane = tid & 63, q = lane >> 4, r15 = lane & 15;
    int arow = w * 16 + r15;

    bf16x8 wf[3][4];
#pragma unroll
    for (int kt = 0; kt < 3; ++kt)
#pragma unroll
        for (int nt = 0; nt < 4; ++nt)
            wf[kt][nt] = *(const bf16x8*)&wpad[(nt * 16 + r15) * 104 + kt * 32 + q * 8];

    const bf16* ahp = an_hi + arow * 64 + q * 8;
    const bf16* alp = an_lo + arow * 64 + q * 8;
    bf16x8 Ah0 = *(const bf16x8*)ahp;
    bf16x8 Ah1 = *(const bf16x8*)(ahp + 32);
    bf16x8 Al0 = *(const bf16x8*)alp;
    bf16x8 Al1 = *(const bf16x8*)(alp + 32);

    float bc[4];
#pragma unroll
    for (int nt = 0; nt < 4; ++nt) bc[nt] = b1[nt * 16 + r15];

    size_t b0 = (size_t)blockIdx.x * 4;
    const f32x4* xb4 = (const f32x4*)(x + b0 * 4288);

    f32x4 pre0 = xb4[tid], pre1 = xb4[tid + 256], pre2 = xb4[tid + 512], pre3 = xb4[tid + 768];
    f32x4 pre4 = {0.f, 0.f, 0.f, 0.f};
    if (tid < 48) pre4 = xb4[tid + 1024];

    f32x4* xl4 = (f32x4*)u.xraw;
    f32x4 z4 = {0.f, 0.f, 0.f, 0.f};

#pragma unroll 1
    for (int g = 0; g < 4; ++g) {
        int b = (int)b0 + g;
        xl4[tid] = pre0; xl4[tid + 256] = pre1; xl4[tid + 512] = pre2; xl4[tid + 768] = pre3;
        if (tid < 48) xl4[tid + 1024] = pre4;
        __syncthreads();                              // B1

        f32x4 acc[4] = {z4, z4, z4, z4};
        const float* xr = u.xraw + arow * FIN_;
#pragma unroll
        for (int kt = 0; kt < 3; ++kt) {
            bf16x8 a;
            if (kt < 2) {
                int k0 = kt * 32 + q * 8;
#pragma unroll
                for (int j = 0; j < 8; ++j) a[j] = (bf16)xr[k0 + j];
            } else {
#pragma unroll
                for (int j = 0; j < 8; ++j) a[j] = (bf16)0.f;
                if (q == 0) { a[0] = (bf16)xr[64]; a[1] = (bf16)xr[65]; a[2] = (bf16)xr[66]; }
            }
#pragma unroll
            for (int nt = 0; nt < 4; ++nt)
                acc[nt] = __builtin_amdgcn_mfma_f32_16x16x32_bf16(a, wf[kt][nt], acc[nt], 0, 0, 0);
        }
        if (g < 3) {
            const f32x4* xn = xb4 + (size_t)(g + 1) * 1072;
            pre0 = xn[tid]; pre1 = xn[tid + 256]; pre2 = xn[tid + 512]; pre3 = xn[tid + 768];
            if (tid < 48) pre4 = xn[tid + 1024];
        }
        __syncthreads();                              // B2

        int sbase = w * 16 + q * 4;
#pragma unroll
        for (int nt = 0; nt < 4; ++nt) {
            int c = nt * 16 + r15;
            bf16x4 hi, lo;
#pragma unroll
            for (int r = 0; r < 4; ++r) {
                float v = acc[nt][r];
                bf16 h = (bf16)v;
                hi[r] = h; lo[r] = (bf16)(v - (float)h);
            }
            *(bf16x4*)&u.h.hhi[c * 72 + sbase] = hi;
            *(bf16x4*)&u.h.hlo[c * 72 + sbase] = lo;
        }
        __syncthreads();                              // B3

        f32x4 acc2[4] = {z4, z4, z4, z4};
#pragma unroll
        for (int kt = 0; kt < 2; ++kt) {
            bf16x8 Ahk = kt ? Ah1 : Ah0;
            bf16x8 Alk = kt ? Al1 : Al0;
#pragma unroll
            for (int nt = 0; nt < 4; ++nt) {
                int o = (nt * 16 + r15) * 72 + kt * 32 + q * 8;
                bf16x8 Hh = *(const bf16x8*)&u.h.hhi[o];
                bf16x8 Hl = *(const bf16x8*)&u.h.hlo[o];
                acc2[nt] = __builtin_amdgcn_mfma_f32_16x16x32_bf16(Ahk, Hh, acc2[nt], 0, 0, 0);
                acc2[nt] = __builtin_amdgcn_mfma_f32_16x16x32_bf16(Ahk, Hl, acc2[nt], 0, 0, 0);
                acc2[nt] = __builtin_amdgcn_mfma_f32_16x16x32_bf16(Alk, Hh, acc2[nt], 0, 0, 0);
            }
        }
#pragma unroll
        for (int nt = 0; nt < 4; ++nt) {
            int c = nt * 16 + r15;
#pragma unroll
            for (int r = 0; r < 4; ++r)
                ost[(sbase + r) * 72 + c] = (bf16)(acc2[nt][r] + bc[nt]);
        }
        __syncthreads();                              // B4

        int n = tid >> 2, oq = tid & 3;
        bf16x8 o0 = *(const bf16x8*)&ost[n * 72 + oq * 16];
        bf16x8 o1 = *(const bf16x8*)&ost[n * 72 + oq * 16 + 8];
        bf16* gp = g1out + ((size_t)b * 4096 + n * 64 + oq * 16);
        *(bf16x8*)gp = o0;
        *(bf16x8*)(gp + 8) = o1;
        float s1 = 0.f, s2 = 0.f;
#pragma unroll
        for (int j = 0; j < 8; ++j) {
            float v0 = (float)o0[j], v1 = (float)o1[j];
            s1 += v0 + v1; s2 += v0 * v0 + v1 * v1;
        }
        s1 += __shfl_xor(s1, 1); s1 += __shfl_xor(s1, 2);
        s2 += __shfl_xor(s2, 1); s2 += __shfl_xor(s2, 2);
        if (oq == 0) {
            int slot = b & (NSLOT - 1);
            atomicAdd(&part1[(slot * 64 + n) * 2 + 0], s1);
            atomicAdd(&part1[(slot * 64 + n) * 2 + 1], s2);
        }
    }
}

// ---------------- BN stats reduce: partials -> scale/shift per node ----------------
__global__ __launch_bounds__(64) void k_bnstats(
    const float* __restrict__ part,
    const float* __restrict__ gamma, const float* __restrict__ beta,
    float* __restrict__ scale, float* __restrict__ shift, float inv_count)
{
    int n = blockIdx.x, t = threadIdx.x;
    float s1 = part[(t * 64 + n) * 2] + part[((t + 64) * 64 + n) * 2];
    float s2 = part[(t * 64 + n) * 2 + 1] + part[((t + 64) * 64 + n) * 2 + 1];
#pragma unroll
    for (int o = 32; o > 0; o >>= 1) { s1 += __shfl_down(s1, o); s2 += __shfl_down(s2, o); }
    if (t == 0) {
        float mean = s1 * inv_count;
        float var = s2 * inv_count - mean * mean;
        float sc = gamma[n] * rsqrtf(var + EPSBN);
        scale[n] = sc;
        shift[n] = beta[n] - mean * sc;
    }
}

// ---------------- K3: BN1+relu fused -> GCN layer 2, 4 batches/block pipelined ----------------
__global__ __launch_bounds__(256, 4) void k3_gcn2(
    const bf16* __restrict__ g1out,
    const float* __restrict__ b2,
    const float* __restrict__ scale1, const float* __restrict__ shift1,
    const bf16* __restrict__ an_hi, const bf16* __restrict__ an_lo,
    const bf16* __restrict__ w2pad,
    bf16* __restrict__ g2out,
    float* __restrict__ part2)
{
    __shared__ bf16 ya[64 * 72];
    __shared__ bf16 hhi[32 * 72];
    __shared__ bf16 hlo[32 * 72];
    __shared__ bf16 ost[64 * 40];

    int tid = threadIdx.x;
    int w = tid >> 6, lane = tid & 63, q = lane >> 4, r15 = lane & 15;
    int arow = w * 16 + r15;

    bf16x8 wf[2][2];
#pragma unroll
    for (int kt = 0; kt < 2; ++kt)
#pragma unroll
        for (int nt = 0; nt < 2; ++nt)
            wf[kt][nt] = *(const bf16x8*)&w2pad[(nt * 16 + r15) * 72 + kt * 32 + q * 8];

    const bf16* ahp = an_hi + arow * 64 + q * 8;
    const bf16* alp = an_lo + arow * 64 + q * 8;
    bf16x8 Ah0 = *(const bf16x8*)ahp;
    bf16x8 Ah1 = *(const bf16x8*)(ahp + 32);
    bf16x8 Al0 = *(const bf16x8*)alp;
    bf16x8 Al1 = *(const bf16x8*)(alp + 32);
    float sc = scale1[arow], sh = shift1[arow];
    float bc[2] = { b2[r15], b2[16 + r15] };

    size_t b0 = (size_t)blockIdx.x * 4;
    const bf16x8* gg8 = (const bf16x8*)(g1out + b0 * 4096);
    bf16x8 p0 = gg8[tid], p1 = gg8[tid + 256];

    int r0 = tid >> 3, c0 = (tid & 7) * 8;
    f32x4 z4 = {0.f, 0.f, 0.f, 0.f};

#pragma unroll 1
    for (int g = 0; g < 4; ++g) {
        int b = (int)b0 + g;
        *(bf16x8*)&ya[r0 * 72 + c0] = p0;
        *(bf16x8*)&ya[(r0 + 32) * 72 + c0] = p1;
        __syncthreads();                              // B1

        f32x4 acc[2] = {z4, z4};
#pragma unroll
        for (int kt = 0; kt < 2; ++kt) {
            int k0 = kt * 32 + q * 8;
            bf16x8 raw = *(const bf16x8*)&ya[arow * 72 + k0];
            bf16x8 a;
#pragma unroll
            for (int j = 0; j < 8; ++j)
                a[j] = (bf16)fmaxf(fmaf(sc, (float)raw[j], sh), 0.f);
#pragma unroll
            for (int nt = 0; nt < 2; ++nt)
                acc[nt] = __builtin_amdgcn_mfma_f32_16x16x32_bf16(a, wf[kt][nt], acc[nt], 0, 0, 0);
        }
        if (g < 3) {
            p0 = gg8[(size_t)(g + 1) * 512 + tid];
            p1 = gg8[(size_t)(g + 1) * 512 + tid + 256];
        }
        __syncthreads();                              // B2

        int sbase = w * 16 + q * 4;
#pragma unroll
        for (int nt = 0; nt < 2; ++nt) {
            int c = nt * 16 + r15;
            bf16x4 hi, lo;
#pragma unroll
            for (int r = 0; r < 4; ++r) {
                float v = acc[nt][r];
                bf16 h = (bf16)v;
                hi[r] = h; lo[r] = (bf16)(v - (float)h);
            }
            *(bf16x4*)&hhi[c * 72 + sbase] = hi;
            *(bf16x4*)&hlo[c * 72 + sbase] = lo;
        }
        __syncthreads();                              // B3

        f32x4 acc2[2] = {z4, z4};
#pragma unroll
        for (int kt = 0; kt < 2; ++kt) {
            bf16x8 Ahk = kt ? Ah1 : Ah0;
            bf16x8 Alk = kt ? Al1 : Al0;
#pragma unroll
            for (int nt = 0; nt < 2; ++nt) {
                int o = (nt * 16 + r15) * 72 + kt * 32 + q * 8;
                bf16x8 Hh = *(const bf16x8*)&hhi[o];
                bf16x8 Hl = *(const bf16x8*)&hlo[o];
                acc2[nt] = __builtin_amdgcn_mfma_f32_16x16x32_bf16(Ahk, Hh, acc2[nt], 0, 0, 0);
                acc2[nt] = __builtin_amdgcn_mfma_f32_16x16x32_bf16(Ahk, Hl, acc2[nt], 0, 0, 0);
                acc2[nt] = __builtin_amdgcn_mfma_f32_16x16x32_bf16(Alk, Hh, acc2[nt], 0, 0, 0);
            }
        }
#pragma unroll
        for (int nt = 0; nt < 2; ++nt) {
            int c = nt * 16 + r15;
#pragma unroll
            for (int r = 0; r < 4; ++r)
                ost[(sbase + r) * 40 + c] = (bf16)(acc2[nt][r] + bc[nt]);
        }
        __syncthreads();                              // B4

        int n = tid >> 2, oq = tid & 3;
        bf16x8 ov = *(const bf16x8*)&ost[n * 40 + oq * 8];
        *(bf16x8*)(g2out + ((size_t)b * 2048 + n * 32 + oq * 8)) = ov;
        float s1 = 0.f, s2 = 0.f;
#pragma unroll
        for (int j = 0; j < 8; ++j) {
            float v = (float)ov[j];
            s1 += v; s2 += v * v;
        }
        s1 += __shfl_xor(s1, 1); s1 += __shfl_xor(s1, 2);
        s2 += __shfl_xor(s2, 1); s2 += __shfl_xor(s2, 2);
        if (oq == 0) {
            int slot = b & (NSLOT - 1);
            atomicAdd(&part2[(slot * 64 + n) * 2 + 0], s1);
            atomicAdd(&part2[(slot * 64 + n) * 2 + 1], s2);
        }
    }
}

// ---------------- K6: MLP1 split-K GEMM — ZERO barriers, ZERO LDS, VGPR-funded depth-2 ------
// grid (64, 7, 4) = 1792 blocks. B pre-converted bf16 (L2-hot), direct frag loads; A streams
// global->reg->cvt. __launch_bounds__(256, 4): min 4 waves/EU -> 128-VGPR budget so the
// depth-2 ping-pong slots (acc 16 + A 16 + B 32 + addr ~= 90 VGPR) stay LIVE. Round-10's
// (256) default targeted 8 waves/EU -> 52 VGPR -> compiler collapsed the pipeline (84 us).
__global__ __launch_bounds__(256, 4) void k6_mlp1(
    const float* __restrict__ A,          // [4096][2048] f32
    const bf16* __restrict__ Bw,          // [448][2048] bf16 (rows >=400 are zero)
    float* __restrict__ part)             // [4][4096][400]
{
    int tid = threadIdx.x;
    int m0 = blockIdx.x * 64, n0 = blockIdx.y * 64, ks = blockIdx.z;
    int w = tid >> 6, lane = tid & 63, q = lane >> 4, r15 = lane & 15;
    f32x4 z4 = {0.f, 0.f, 0.f, 0.f};
    f32x4 acc[4] = {z4, z4, z4, z4};

    const float* pA = A + (size_t)(m0 + w * 16 + r15) * 2048 + ks * 512 + q * 8;
    const bf16* pB0 = Bw + (size_t)(n0 + r15) * 2048 + ks * 512 + q * 8;
    const bf16* pB1 = pB0 + 16 * 2048;
    const bf16* pB2 = pB0 + 32 * 2048;
    const bf16* pB3 = pB0 + 48 * 2048;

    f32x4 aA0, aA1, bA0, bA1;                         // A slots (f32, cvt at use)
    bf16x8 aB0, aB1, aB2, aB3, bB0, bB1, bB2, bB3;    // B slots (bf16, direct frag)

#define LD0(t) do { \
        aA0 = *(const f32x4*)(pA + (t) * 32); aA1 = *(const f32x4*)(pA + (t) * 32 + 4); \
        aB0 = *(const bf16x8*)(pB0 + (t) * 32); aB1 = *(const bf16x8*)(pB1 + (t) * 32); \
        aB2 = *(const bf16x8*)(pB2 + (t) * 32); aB3 = *(const bf16x8*)(pB3 + (t) * 32); \
    } while (0)
#define LD1(t) do { \
        bA0 = *(const f32x4*)(pA + (t) * 32); bA1 = *(const f32x4*)(pA + (t) * 32 + 4); \
        bB0 = *(const bf16x8*)(pB0 + (t) * 32); bB1 = *(const bf16x8*)(pB1 + (t) * 32); \
        bB2 = *(const bf16x8*)(pB2 + (t) * 32); bB3 = *(const bf16x8*)(pB3 + (t) * 32); \
    } while (0)

    LD0(0); LD1(1);
#pragma unroll
    for (int t = 0; t < 16; t += 2) {
        bf16x8 af0 = pack8(aA0, aA1);
        acc[0] = __builtin_amdgcn_mfma_f32_16x16x32_bf16(af0, aB0, acc[0], 0, 0, 0);
        acc[1] = __builtin_amdgcn_mfma_f32_16x16x32_bf16(af0, aB1, acc[1], 0, 0, 0);
        acc[2] = __builtin_amdgcn_mfma_f32_16x16x32_bf16(af0, aB2, acc[2], 0, 0, 0);
        acc[3] = __builtin_amdgcn_mfma_f32_16x16x32_bf16(af0, aB3, acc[3], 0, 0, 0);
        if (t + 2 < 16) LD0(t + 2);
        bf16x8 af1 = pack8(bA0, bA1);
        acc[0] = __builtin_amdgcn_mfma_f32_16x16x32_bf16(af1, bB0, acc[0], 0, 0, 0);
        acc[1] = __builtin_amdgcn_mfma_f32_16x16x32_bf16(af1, bB1, acc[1], 0, 0, 0);
        acc[2] = __builtin_amdgcn_mfma_f32_16x16x32_bf16(af1, bB2, acc[2], 0, 0, 0);
        acc[3] = __builtin_amdgcn_mfma_f32_16x16x32_bf16(af1, bB3, acc[3], 0, 0, 0);
        if (t + 3 < 16) LD1(t + 3);
    }
#undef LD0
#undef LD1

    float* pp = part + (size_t)ks * 1638400;
#pragma unroll
    for (int nt = 0; nt < 4; ++nt) {
        int nn = n0 + nt * 16 + r15;
        if (nn < 400) {
#pragma unroll
            for (int r = 0; r < 4; ++r) {
                int mm = m0 + w * 16 + q * 4 + r;
                pp[(size_t)mm * 400 + nn] = acc[nt][r];
            }
        }
    }
}

// ---------------- K7: fused split-K reduce + bias + relu + MLP2 GEMM ----------------
__global__ __launch_bounds__(256) void k7_mlp2(
    const float* __restrict__ part,       // [4][4096][400] f32
    const float* __restrict__ bl1,        // [400]
    const float* __restrict__ Bw,         // [64][400] f32 (Wl2)
    const float* __restrict__ bias,       // [64] (bl2)
    float* __restrict__ Cout)             // [4096][64]
{
    __shared__ bf16 As[16 * 416];
    int tid = threadIdx.x;
    int m0 = blockIdx.x * 16;
    for (int i = tid; i < 800; i += 256) {
        int rr = i / 50, cc = (i % 50) * 8;
        const float* p0 = part + (size_t)(m0 + rr) * 400 + cc;
        f32x4 x0 = *(const f32x4*)p0,             x1 = *(const f32x4*)(p0 + 4);
        f32x4 y0 = *(const f32x4*)(p0 + 1638400), y1 = *(const f32x4*)(p0 + 1638404);
        f32x4 u0 = *(const f32x4*)(p0 + 3276800), u1 = *(const f32x4*)(p0 + 3276804);
        f32x4 v0 = *(const f32x4*)(p0 + 4915200), v1 = *(const f32x4*)(p0 + 4915204);
        f32x4 w0 = *(const f32x4*)&bl1[cc],       w1 = *(const f32x4*)&bl1[cc + 4];
        bf16x8 o;
#pragma unroll
        for (int j = 0; j < 4; ++j) {
            o[j]     = (bf16)fmaxf(x0[j] + y0[j] + u0[j] + v0[j] + w0[j], 0.f);
            o[4 + j] = (bf16)fmaxf(x1[j] + y1[j] + u1[j] + v1[j] + w1[j], 0.f);
        }
        *(bf16x8*)&As[rr * 416 + cc] = o;
    }
    if (tid < 32) {
        int rr = tid >> 1, cc = 400 + (tid & 1) * 8;
        bf16x8 z;
#pragma unroll
        for (int k = 0; k < 8; ++k) z[k] = (bf16)0.f;
        *(bf16x8*)&As[rr * 416 + cc] = z;
    }
    __syncthreads();

    int w = tid >> 6, lane = tid & 63, q = lane >> 4, r15 = lane & 15;
    f32x4 acc = {0.f, 0.f, 0.f, 0.f};
    const float* pB = Bw + (size_t)(w * 16 + r15) * 400;
#pragma unroll 4
    for (int kt = 0; kt < 13; ++kt) {
        int k0 = kt * 32 + q * 8;
        bf16x8 a = *(const bf16x8*)&As[r15 * 416 + k0];
        bf16x8 bb;
#pragma unroll
        for (int k = 0; k < 8; ++k) bb[k] = (bf16)0.f;
        if (k0 < 400) {
            f32x4 c0 = *(const f32x4*)(pB + k0);
            f32x4 c1 = *(const f32x4*)(pB + k0 + 4);
            bb[0] = (bf16)c0[0]; bb[1] = (bf16)c0[1]; bb[2] = (bf16)c0[2]; bb[3] = (bf16)c0[3];
            bb[4] = (bf16)c1[0]; bb[5] = (bf16)c1[1]; bb[6] = (bf16)c1[2]; bb[7] = (bf16)c1[3];
        }
        acc = __builtin_amdgcn_mfma_f32_16x16x32_bf16(a, bb, acc, 0, 0, 0);
    }
#pragma unroll
    for (int r = 0; r < 4; ++r) {
        int mm = m0 + q * 4 + r;
        int nn = w * 16 + r15;
        float v = fmaxf(acc[r] + bias[nn], 0.f);
        Cout[(size_t)mm * 64 + nn] = v;
    }
}

// ---------------- K8: BN2+relu+maxpool + concat + FC ----------------
__global__ __launch_bounds__(256) void k8_final(
    const bf16* __restrict__ g2out,
    const float* __restrict__ scale2, const float* __restrict__ shift2,
    const float* __restrict__ h2,
    const float* __restrict__ Wfc,
    const float* __restrict__ bfc,
    float* __restrict__ out)
{
    __shared__ float s2s[64], sh2s[64];
    int tid = threadIdx.x;
    if (tid < 64) { s2s[tid] = scale2[tid]; sh2s[tid] = shift2[tid]; }
    __syncthreads();
    int w = tid >> 6, lane = tid & 63;
    int b = blockIdx.x * 4 + w;
    int c = lane & 31, half = lane >> 5;
    const bf16* gb = g2out + (size_t)b * 2048;
    float mx = 0.f;
    for (int i = 0; i < 32; ++i) {
        int n = half * 32 + i;
        float v = (float)gb[n * 32 + c];
        float val = fmaf(s2s[n], v, sh2s[n]);
        mx = fmaxf(mx, val);
    }
    mx = fmaxf(mx, __shfl_xor(mx, 32));
    float h2v = h2[(size_t)b * 64 + lane];
#pragma unroll
    for (int o = 0; o < 2; ++o) {
        float t = h2v * Wfc[o * 96 + 32 + lane];
        if (half == 0) t += mx * Wfc[o * 96 + c];
#pragma unroll
        for (int off = 32; off > 0; off >>= 1) t += __shfl_xor(t, off);
        if (lane == 0) out[(size_t)b * 2 + o] = t + bfc[o];
    }
}

extern "C" void kernel_launch(void* const* d_in, const int* in_sizes, int n_in,
                              void* d_out, int out_size, void* d_ws, size_t ws_size,
                              hipStream_t stream)
{
    const float* x_fp   = (const float*)d_in[0];
    const float* x_node = (const float*)d_in[1];
    const int*   edge   = (const int*)d_in[2];
    const float* W1     = (const float*)d_in[3];
    const float* b1     = (const float*)d_in[4];
    const float* g1     = (const float*)d_in[5];
    const float* be1    = (const float*)d_in[6];
    const float* W2     = (const float*)d_in[7];
    const float* b2     = (const float*)d_in[8];
    const float* g2     = (const float*)d_in[9];
    const float* be2    = (const float*)d_in[10];
    const float* Wl1    = (const float*)d_in[11];
    const float* bl1    = (const float*)d_in[12];
    const float* Wl2    = (const float*)d_in[13];
    const float* bl2    = (const float*)d_in[14];
    const float* Wfc    = (const float*)d_in[15];
    const float* bfc    = (const float*)d_in[16];
    float* out = (float*)d_out;

    char* ws = (char*)d_ws;
    float* scale1  = (float*)(ws + 5632);
    float* shift1  = (float*)(ws + 5888);
    float* scale2  = (float*)(ws + 6144);
    float* shift2  = (float*)(ws + 6400);
    float* part1   = (float*)(ws + 8192);             // 65536 B
    float* part2   = (float*)(ws + 8192 + 65536);     // 65536 B
    bf16*  g1out   = (bf16*)(ws + 139264);            // 33554432 B (dead after k3 -> reused as part6)
    float* part6   = (float*)(ws + 139264);           // 26214400 B, overlays g1out
    bf16*  g2out   = (bf16*)(ws + 33693696ull);       // 16777216 B
    float* h2      = (float*)(ws + 53747712ull);      // 1048576 B
    // An + padded weight tables overlay the h2 region (dead before k7 writes h2).
    bf16*  an_hi   = (bf16*)(ws + 53747712ull);               // 8192 B
    bf16*  an_lo   = (bf16*)(ws + 53747712ull + 8192);        // 8192 B
    bf16*  wpad    = (bf16*)(ws + 53747712ull + 16384);       // 13312 B
    bf16*  w2pad   = (bf16*)(ws + 53747712ull + 32768);       // 4608 B
    bf16*  wl1b    = (bf16*)(ws + 58720256ull);               // 1835008 B: bf16 Wl1 [448][2048]

    k0_prep<<<dim3(64), dim3(256), 0, stream>>>(edge, W1, W2, Wl1, part1,
                                                an_hi, an_lo, wpad, w2pad, wl1b);
    k1_gcn1<<<dim3(1024), dim3(256), 0, stream>>>(x_node, b1, an_hi, an_lo, wpad, g1out, part1);
    k_bnstats<<<dim3(64), dim3(64), 0, stream>>>(part1, g1, be1, scale1, shift1,
                                                 1.f / (4096.f * 64.f));
    k3_gcn2<<<dim3(1024), dim3(256), 0, stream>>>(g1out, b2, scale1, shift1,
                                                  an_hi, an_lo, w2pad, g2out, part2);
    k_bnstats<<<dim3(64), dim3(64), 0, stream>>>(part2, g2, be2, scale2, shift2,
                                                 1.f / (4096.f * 32.f));
    // g1out is dead now; k6 writes split-K partials into its space
    k6_mlp1<<<dim3(64, 7, 4), dim3(256), 0, stream>>>(x_fp, wl1b, part6);
    k7_mlp2<<<dim3(256), dim3(256), 0, stream>>>(part6, bl1, Wl2, bl2, h2);
    k8_final<<<dim3(1024), dim3(256), 0, stream>>>(g2out, scale2, shift2, h2, Wfc, bfc, out);
}

// Round 13
// 235.643 us; speedup vs baseline: 1.2154x; 1.2154x over previous
//
#include <hip/hip_runtime.h>
#include <hip/hip_bf16.h>
#include <math.h>

typedef __bf16 bf16;
typedef __attribute__((ext_vector_type(8))) __bf16 bf16x8;
typedef __attribute__((ext_vector_type(4))) __bf16 bf16x4;
typedef __attribute__((ext_vector_type(4))) float f32x4;

#define EPSBN 1e-5f
#define B_    4096
#define N_    64
#define FIN_  67
#define E_    512
#define NSLOT 128

__device__ inline bf16x8 pack8(f32x4 lo, f32x4 hi) {
    bf16x8 r;
    r[0] = (bf16)lo[0]; r[1] = (bf16)lo[1]; r[2] = (bf16)lo[2]; r[3] = (bf16)lo[3];
    r[4] = (bf16)hi[0]; r[5] = (bf16)hi[1]; r[6] = (bf16)hi[2]; r[7] = (bf16)hi[3];
    return r;
}

// ---------------- K0: adjacency + padded weights + Wl1->bf16 prepack + zero partials ----------
// blocks 0:An  1:wpad  2:w2pad  3..63: wl1b = bf16(Wl1) padded to [448][2048] (rows>=400 zero)
__global__ __launch_bounds__(256) void k0_prep(const int* __restrict__ edge,
    const float* __restrict__ W1, const float* __restrict__ W2,
    const float* __restrict__ Wl1,
    float* __restrict__ partials,
    bf16* __restrict__ an_hi, bf16* __restrict__ an_lo,
    bf16* __restrict__ wpad,               // [64][104] bf16
    bf16* __restrict__ w2pad,              // [32][72]  bf16
    bf16* __restrict__ wl1b)               // [448][2048] bf16
{
    int tid = threadIdx.x;
    for (int i = blockIdx.x * 256 + tid; i < NSLOT * 64 * 4; i += gridDim.x * 256)
        partials[i] = 0.f;
    if (blockIdx.x == 1) {
        for (int i = tid; i < 64 * 104; i += 256) {
            int n = i / 104, f = i % 104;
            wpad[i] = (f < FIN_) ? (bf16)W1[n * FIN_ + f] : (bf16)0.f;
        }
        return;
    }
    if (blockIdx.x == 2) {
        for (int i = tid; i < 32 * 72; i += 256) {
            int o = i / 72, f = i % 72;
            w2pad[i] = (f < 64) ? (bf16)W2[o * 64 + f] : (bf16)0.f;
        }
        return;
    }
    if (blockIdx.x >= 3) {                            // 61 blocks: Wl1 -> bf16 [448][2048]
        for (int i = (blockIdx.x - 3) * 256 + tid; i < 448 * 256; i += 61 * 256) {
            int row = i >> 8, col = (i & 255) * 8;    // 256 bf16x8 chunks per row
            bf16x8 o;
            if (row < 400) {
                const float* p = Wl1 + (size_t)row * 2048 + col;
                o = pack8(*(const f32x4*)p, *(const f32x4*)(p + 4));
            } else {
#pragma unroll
                for (int k = 0; k < 8; ++k) o[k] = (bf16)0.f;
            }
            *(bf16x8*)&wl1b[(size_t)row * 2048 + col] = o;
        }
        return;
    }

    __shared__ float An[64 * 64];
    __shared__ int ssrc[E_], sdst[E_];
    __shared__ int deg[N_];
    __shared__ float dinv[N_];
    for (int i = tid; i < 64 * 64; i += 256) An[i] = 0.f;
    for (int i = tid; i < E_; i += 256) { ssrc[i] = edge[i]; sdst[i] = edge[E_ + i]; }
    if (tid < N_) deg[tid] = 1;                       // self loop contributes 1
    __syncthreads();
    for (int i = tid; i < E_; i += 256) atomicAdd(&deg[sdst[i]], 1);
    __syncthreads();
    if (tid < N_) dinv[tid] = rsqrtf((float)deg[tid]);
    __syncthreads();
    for (int i = tid; i < E_; i += 256) {
        int s = ssrc[i], d = sdst[i];
        atomicAdd(&An[d * 64 + s], dinv[s] * dinv[d]);
    }
    if (tid < N_) atomicAdd(&An[tid * 64 + tid], dinv[tid] * dinv[tid]);
    __syncthreads();
    for (int i = tid; i < 64 * 64; i += 256) {
        float v = An[i];
        bf16 h = (bf16)v;
        an_hi[i] = h;
        an_lo[i] = (bf16)(v - (float)h);
    }
}

// ---------------- K1: GCN layer 1, 4 batches/block, reg-prefetch pipelined ----------------
__global__ __launch_bounds__(256, 3) void k1_gcn1(
    const float* __restrict__ x,          // [B][64][67]
    const float* __restrict__ b1,
    const bf16* __restrict__ an_hi, const bf16* __restrict__ an_lo,
    const bf16* __restrict__ wpad,        // [64][104] bf16
    bf16* __restrict__ g1out,             // [B][64][64]
    float* __restrict__ part1)            // [NSLOT][64][2]
{
    __shared__ union {
        float xraw[4352];
        struct { bf16 hhi[64 * 72]; bf16 hlo[64 * 72]; } h;
    } u;
    __shared__ bf16 ost[64 * 72];

    int tid = threadIdx.x;
    int w = tid >> 6, lane = tid & 63, q = lane >> 4, r15 = lane & 15;
    int arow = w * 16 + r15;

    bf16x8 wf[3][4];
#pragma unroll
    for (int kt = 0; kt < 3; ++kt)
#pragma unroll
        for (int nt = 0; nt < 4; ++nt)
            wf[kt][nt] = *(const bf16x8*)&wpad[(nt * 16 + r15) * 104 + kt * 32 + q * 8];

    const bf16* ahp = an_hi + arow * 64 + q * 8;
    const bf16* alp = an_lo + arow * 64 + q * 8;
    bf16x8 Ah0 = *(const bf16x8*)ahp;
    bf16x8 Ah1 = *(const bf16x8*)(ahp + 32);
    bf16x8 Al0 = *(const bf16x8*)alp;
    bf16x8 Al1 = *(const bf16x8*)(alp + 32);

    float bc[4];
#pragma unroll
    for (int nt = 0; nt < 4; ++nt) bc[nt] = b1[nt * 16 + r15];

    size_t b0 = (size_t)blockIdx.x * 4;
    const f32x4* xb4 = (const f32x4*)(x + b0 * 4288);

    f32x4 pre0 = xb4[tid], pre1 = xb4[tid + 256], pre2 = xb4[tid + 512], pre3 = xb4[tid + 768];
    f32x4 pre4 = {0.f, 0.f, 0.f, 0.f};
    if (tid < 48) pre4 = xb4[tid + 1024];

    f32x4* xl4 = (f32x4*)u.xraw;
    f32x4 z4 = {0.f, 0.f, 0.f, 0.f};

#pragma unroll 1
    for (int g = 0; g < 4; ++g) {
        int b = (int)b0 + g;
        xl4[tid] = pre0; xl4[tid + 256] = pre1; xl4[tid + 512] = pre2; xl4[tid + 768] = pre3;
        if (tid < 48) xl4[tid + 1024] = pre4;
        __syncthreads();                              // B1

        f32x4 acc[4] = {z4, z4, z4, z4};
        const float* xr = u.xraw + arow * FIN_;
#pragma unroll
        for (int kt = 0; kt < 3; ++kt) {
            bf16x8 a;
            if (kt < 2) {
                int k0 = kt * 32 + q * 8;
#pragma unroll
                for (int j = 0; j < 8; ++j) a[j] = (bf16)xr[k0 + j];
            } else {
#pragma unroll
                for (int j = 0; j < 8; ++j) a[j] = (bf16)0.f;
                if (q == 0) { a[0] = (bf16)xr[64]; a[1] = (bf16)xr[65]; a[2] = (bf16)xr[66]; }
            }
#pragma unroll
            for (int nt = 0; nt < 4; ++nt)
                acc[nt] = __builtin_amdgcn_mfma_f32_16x16x32_bf16(a, wf[kt][nt], acc[nt], 0, 0, 0);
        }
        if (g < 3) {
            const f32x4* xn = xb4 + (size_t)(g + 1) * 1072;
            pre0 = xn[tid]; pre1 = xn[tid + 256]; pre2 = xn[tid + 512]; pre3 = xn[tid + 768];
            if (tid < 48) pre4 = xn[tid + 1024];
        }
        __syncthreads();                              // B2

        int sbase = w * 16 + q * 4;
#pragma unroll
        for (int nt = 0; nt < 4; ++nt) {
            int c = nt * 16 + r15;
            bf16x4 hi, lo;
#pragma unroll
            for (int r = 0; r < 4; ++r) {
                float v = acc[nt][r];
                bf16 h = (bf16)v;
                hi[r] = h; lo[r] = (bf16)(v - (float)h);
            }
            *(bf16x4*)&u.h.hhi[c * 72 + sbase] = hi;
            *(bf16x4*)&u.h.hlo[c * 72 + sbase] = lo;
        }
        __syncthreads();                              // B3

        f32x4 acc2[4] = {z4, z4, z4, z4};
#pragma unroll
        for (int kt = 0; kt < 2; ++kt) {
            bf16x8 Ahk = kt ? Ah1 : Ah0;
            bf16x8 Alk = kt ? Al1 : Al0;
#pragma unroll
            for (int nt = 0; nt < 4; ++nt) {
                int o = (nt * 16 + r15) * 72 + kt * 32 + q * 8;
                bf16x8 Hh = *(const bf16x8*)&u.h.hhi[o];
                bf16x8 Hl = *(const bf16x8*)&u.h.hlo[o];
                acc2[nt] = __builtin_amdgcn_mfma_f32_16x16x32_bf16(Ahk, Hh, acc2[nt], 0, 0, 0);
                acc2[nt] = __builtin_amdgcn_mfma_f32_16x16x32_bf16(Ahk, Hl, acc2[nt], 0, 0, 0);
                acc2[nt] = __builtin_amdgcn_mfma_f32_16x16x32_bf16(Alk, Hh, acc2[nt], 0, 0, 0);
            }
        }
#pragma unroll
        for (int nt = 0; nt < 4; ++nt) {
            int c = nt * 16 + r15;
#pragma unroll
            for (int r = 0; r < 4; ++r)
                ost[(sbase + r) * 72 + c] = (bf16)(acc2[nt][r] + bc[nt]);
        }
        __syncthreads();                              // B4

        int n = tid >> 2, oq = tid & 3;
        bf16x8 o0 = *(const bf16x8*)&ost[n * 72 + oq * 16];
        bf16x8 o1 = *(const bf16x8*)&ost[n * 72 + oq * 16 + 8];
        bf16* gp = g1out + ((size_t)b * 4096 + n * 64 + oq * 16);
        *(bf16x8*)gp = o0;
        *(bf16x8*)(gp + 8) = o1;
        float s1 = 0.f, s2 = 0.f;
#pragma unroll
        for (int j = 0; j < 8; ++j) {
            float v0 = (float)o0[j], v1 = (float)o1[j];
            s1 += v0 + v1; s2 += v0 * v0 + v1 * v1;
        }
        s1 += __shfl_xor(s1, 1); s1 += __shfl_xor(s1, 2);
        s2 += __shfl_xor(s2, 1); s2 += __shfl_xor(s2, 2);
        if (oq == 0) {
            int slot = b & (NSLOT - 1);
            atomicAdd(&part1[(slot * 64 + n) * 2 + 0], s1);
            atomicAdd(&part1[(slot * 64 + n) * 2 + 1], s2);
        }
    }
}

// ---------------- BN stats reduce: partials -> scale/shift per node ----------------
__global__ __launch_bounds__(64) void k_bnstats(
    const float* __restrict__ part,
    const float* __restrict__ gamma, const float* __restrict__ beta,
    float* __restrict__ scale, float* __restrict__ shift, float inv_count)
{
    int n = blockIdx.x, t = threadIdx.x;
    float s1 = part[(t * 64 + n) * 2] + part[((t + 64) * 64 + n) * 2];
    float s2 = part[(t * 64 + n) * 2 + 1] + part[((t + 64) * 64 + n) * 2 + 1];
#pragma unroll
    for (int o = 32; o > 0; o >>= 1) { s1 += __shfl_down(s1, o); s2 += __shfl_down(s2, o); }
    if (t == 0) {
        float mean = s1 * inv_count;
        float var = s2 * inv_count - mean * mean;
        float sc = gamma[n] * rsqrtf(var + EPSBN);
        scale[n] = sc;
        shift[n] = beta[n] - mean * sc;
    }
}

// ---------------- K3: BN1+relu fused -> GCN layer 2, 4 batches/block pipelined ----------------
__global__ __launch_bounds__(256, 4) void k3_gcn2(
    const bf16* __restrict__ g1out,
    const float* __restrict__ b2,
    const float* __restrict__ scale1, const float* __restrict__ shift1,
    const bf16* __restrict__ an_hi, const bf16* __restrict__ an_lo,
    const bf16* __restrict__ w2pad,
    bf16* __restrict__ g2out,
    float* __restrict__ part2)
{
    __shared__ bf16 ya[64 * 72];
    __shared__ bf16 hhi[32 * 72];
    __shared__ bf16 hlo[32 * 72];
    __shared__ bf16 ost[64 * 40];

    int tid = threadIdx.x;
    int w = tid >> 6, lane = tid & 63, q = lane >> 4, r15 = lane & 15;
    int arow = w * 16 + r15;

    bf16x8 wf[2][2];
#pragma unroll
    for (int kt = 0; kt < 2; ++kt)
#pragma unroll
        for (int nt = 0; nt < 2; ++nt)
            wf[kt][nt] = *(const bf16x8*)&w2pad[(nt * 16 + r15) * 72 + kt * 32 + q * 8];

    const bf16* ahp = an_hi + arow * 64 + q * 8;
    const bf16* alp = an_lo + arow * 64 + q * 8;
    bf16x8 Ah0 = *(const bf16x8*)ahp;
    bf16x8 Ah1 = *(const bf16x8*)(ahp + 32);
    bf16x8 Al0 = *(const bf16x8*)alp;
    bf16x8 Al1 = *(const bf16x8*)(alp + 32);
    float sc = scale1[arow], sh = shift1[arow];
    float bc[2] = { b2[r15], b2[16 + r15] };

    size_t b0 = (size_t)blockIdx.x * 4;
    const bf16x8* gg8 = (const bf16x8*)(g1out + b0 * 4096);
    bf16x8 p0 = gg8[tid], p1 = gg8[tid + 256];

    int r0 = tid >> 3, c0 = (tid & 7) * 8;
    f32x4 z4 = {0.f, 0.f, 0.f, 0.f};

#pragma unroll 1
    for (int g = 0; g < 4; ++g) {
        int b = (int)b0 + g;
        *(bf16x8*)&ya[r0 * 72 + c0] = p0;
        *(bf16x8*)&ya[(r0 + 32) * 72 + c0] = p1;
        __syncthreads();                              // B1

        f32x4 acc[2] = {z4, z4};
#pragma unroll
        for (int kt = 0; kt < 2; ++kt) {
            int k0 = kt * 32 + q * 8;
            bf16x8 raw = *(const bf16x8*)&ya[arow * 72 + k0];
            bf16x8 a;
#pragma unroll
            for (int j = 0; j < 8; ++j)
                a[j] = (bf16)fmaxf(fmaf(sc, (float)raw[j], sh), 0.f);
#pragma unroll
            for (int nt = 0; nt < 2; ++nt)
                acc[nt] = __builtin_amdgcn_mfma_f32_16x16x32_bf16(a, wf[kt][nt], acc[nt], 0, 0, 0);
        }
        if (g < 3) {
            p0 = gg8[(size_t)(g + 1) * 512 + tid];
            p1 = gg8[(size_t)(g + 1) * 512 + tid + 256];
        }
        __syncthreads();                              // B2

        int sbase = w * 16 + q * 4;
#pragma unroll
        for (int nt = 0; nt < 2; ++nt) {
            int c = nt * 16 + r15;
            bf16x4 hi, lo;
#pragma unroll
            for (int r = 0; r < 4; ++r) {
                float v = acc[nt][r];
                bf16 h = (bf16)v;
                hi[r] = h; lo[r] = (bf16)(v - (float)h);
            }
            *(bf16x4*)&hhi[c * 72 + sbase] = hi;
            *(bf16x4*)&hlo[c * 72 + sbase] = lo;
        }
        __syncthreads();                              // B3

        f32x4 acc2[2] = {z4, z4};
#pragma unroll
        for (int kt = 0; kt < 2; ++kt) {
            bf16x8 Ahk = kt ? Ah1 : Ah0;
            bf16x8 Alk = kt ? Al1 : Al0;
#pragma unroll
            for (int nt = 0; nt < 2; ++nt) {
                int o = (nt * 16 + r15) * 72 + kt * 32 + q * 8;
                bf16x8 Hh = *(const bf16x8*)&hhi[o];
                bf16x8 Hl = *(const bf16x8*)&hlo[o];
                acc2[nt] = __builtin_amdgcn_mfma_f32_16x16x32_bf16(Ahk, Hh, acc2[nt], 0, 0, 0);
                acc2[nt] = __builtin_amdgcn_mfma_f32_16x16x32_bf16(Ahk, Hl, acc2[nt], 0, 0, 0);
                acc2[nt] = __builtin_amdgcn_mfma_f32_16x16x32_bf16(Alk, Hh, acc2[nt], 0, 0, 0);
            }
        }
#pragma unroll
        for (int nt = 0; nt < 2; ++nt) {
            int c = nt * 16 + r15;
#pragma unroll
            for (int r = 0; r < 4; ++r)
                ost[(sbase + r) * 40 + c] = (bf16)(acc2[nt][r] + bc[nt]);
        }
        __syncthreads();                              // B4

        int n = tid >> 2, oq = tid & 3;
        bf16x8 ov = *(const bf16x8*)&ost[n * 40 + oq * 8];
        *(bf16x8*)(g2out + ((size_t)b * 2048 + n * 32 + oq * 8)) = ov;
        float s1 = 0.f, s2 = 0.f;
#pragma unroll
        for (int j = 0; j < 8; ++j) {
            float v = (float)ov[j];
            s1 += v; s2 += v * v;
        }
        s1 += __shfl_xor(s1, 1); s1 += __shfl_xor(s1, 2);
        s2 += __shfl_xor(s2, 1); s2 += __shfl_xor(s2, 2);
        if (oq == 0) {
            int slot = b & (NSLOT - 1);
            atomicAdd(&part2[(slot * 64 + n) * 2 + 0], s1);
            atomicAdd(&part2[(slot * 64 + n) * 2 + 1], s2);
        }
    }
}

// ---------------- K6: MLP1 split-K GEMM — proven staged skeleton, BK=64 (half the barriers) --
// grid (64, 7, 4) = 1792 blocks. 8 iterations x 2 barriers (vs 16x2 in round-8's 44.5us).
// B from wl1b (bf16, padded): half the B bytes, no pack, no bvalid. Live state ~56-64 VGPR
// fits the compiler's occupancy-greedy budget, so the depth-1 prefetch survives scheduling.
__global__ __launch_bounds__(256) void k6_mlp1(
    const float* __restrict__ A,          // [4096][2048] f32
    const bf16* __restrict__ Bw,          // [448][2048] bf16 (wl1b, rows >=400 zero)
    float* __restrict__ part)             // [4][4096][400]
{
    __shared__ bf16 As[64 * 68];          // pitch 68 bf16 = 136B (34 dwords: 2-4 way banks)
    __shared__ bf16 Bs[64 * 68];
    int tid = threadIdx.x;
    int m0 = blockIdx.x * 64, n0 = blockIdx.y * 64, ks = blockIdx.z;
    int row = tid >> 2, seg = tid & 3;                // 4 segs x 16 k-values per row
    int w = tid >> 6, lane = tid & 63, q = lane >> 4, r15 = lane & 15;
    f32x4 z4 = {0.f, 0.f, 0.f, 0.f};
    f32x4 acc[4] = {z4, z4, z4, z4};
    const float* pA = A + (size_t)(m0 + row) * 2048 + ks * 512 + seg * 16;
    const bf16* pB = Bw + (size_t)(n0 + row) * 2048 + ks * 512 + seg * 16;

    // prologue: iteration-0 loads (A: 16 f32, B: 16 bf16 per thread)
    f32x4 a0 = *(const f32x4*)pA,        a1 = *(const f32x4*)(pA + 4);
    f32x4 a2 = *(const f32x4*)(pA + 8),  a3 = *(const f32x4*)(pA + 12);
    bf16x8 e0 = *(const bf16x8*)pB,      e1 = *(const bf16x8*)(pB + 8);

#pragma unroll
    for (int it = 0; it < 8; ++it) {
        bf16x8 ap0 = pack8(a0, a1), ap1 = pack8(a2, a3);  // waits this iter's loads only
        bf16x8 bp0 = e0, bp1 = e1;
        __syncthreads();                              // prior iter's LDS reads done
        *(bf16x8*)&As[row * 68 + seg * 16]     = ap0;
        *(bf16x8*)&As[row * 68 + seg * 16 + 8] = ap1;
        *(bf16x8*)&Bs[row * 68 + seg * 16]     = bp0;
        *(bf16x8*)&Bs[row * 68 + seg * 16 + 8] = bp1;
        __syncthreads();                              // tiles visible
        if (it < 7) {                                 // depth-1 prefetch: hides under MFMAs
            const float* qA = pA + (it + 1) * 64;
            const bf16*  qB = pB + (it + 1) * 64;
            a0 = *(const f32x4*)qA;       a1 = *(const f32x4*)(qA + 4);
            a2 = *(const f32x4*)(qA + 8); a3 = *(const f32x4*)(qA + 12);
            e0 = *(const bf16x8*)qB;      e1 = *(const bf16x8*)(qB + 8);
        }
#pragma unroll
        for (int h = 0; h < 2; ++h) {
            bf16x8 af = *(const bf16x8*)&As[(w * 16 + r15) * 68 + h * 32 + q * 8];
#pragma unroll
            for (int nt = 0; nt < 4; ++nt) {
                bf16x8 bb = *(const bf16x8*)&Bs[(nt * 16 + r15) * 68 + h * 32 + q * 8];
                acc[nt] = __builtin_amdgcn_mfma_f32_16x16x32_bf16(af, bb, acc[nt], 0, 0, 0);
            }
        }
    }

    float* pp = part + (size_t)ks * 1638400;
#pragma unroll
    for (int nt = 0; nt < 4; ++nt) {
        int nn = n0 + nt * 16 + r15;
        if (nn < 400) {
#pragma unroll
            for (int r = 0; r < 4; ++r) {
                int mm = m0 + w * 16 + q * 4 + r;
                pp[(size_t)mm * 400 + nn] = acc[nt][r];
            }
        }
    }
}

// ---------------- K7: fused split-K reduce + bias + relu + MLP2 GEMM ----------------
__global__ __launch_bounds__(256) void k7_mlp2(
    const float* __restrict__ part,       // [4][4096][400] f32
    const float* __restrict__ bl1,        // [400]
    const float* __restrict__ Bw,         // [64][400] f32 (Wl2)
    const float* __restrict__ bias,       // [64] (bl2)
    float* __restrict__ Cout)             // [4096][64]
{
    __shared__ bf16 As[16 * 416];
    int tid = threadIdx.x;
    int m0 = blockIdx.x * 16;
    for (int i = tid; i < 800; i += 256) {
        int rr = i / 50, cc = (i % 50) * 8;
        const float* p0 = part + (size_t)(m0 + rr) * 400 + cc;
        f32x4 x0 = *(const f32x4*)p0,             x1 = *(const f32x4*)(p0 + 4);
        f32x4 y0 = *(const f32x4*)(p0 + 1638400), y1 = *(const f32x4*)(p0 + 1638404);
        f32x4 u0 = *(const f32x4*)(p0 + 3276800), u1 = *(const f32x4*)(p0 + 3276804);
        f32x4 v0 = *(const f32x4*)(p0 + 4915200), v1 = *(const f32x4*)(p0 + 4915204);
        f32x4 w0 = *(const f32x4*)&bl1[cc],       w1 = *(const f32x4*)&bl1[cc + 4];
        bf16x8 o;
#pragma unroll
        for (int j = 0; j < 4; ++j) {
            o[j]     = (bf16)fmaxf(x0[j] + y0[j] + u0[j] + v0[j] + w0[j], 0.f);
            o[4 + j] = (bf16)fmaxf(x1[j] + y1[j] + u1[j] + v1[j] + w1[j], 0.f);
        }
        *(bf16x8*)&As[rr * 416 + cc] = o;
    }
    if (tid < 32) {
        int rr = tid >> 1, cc = 400 + (tid & 1) * 8;
        bf16x8 z;
#pragma unroll
        for (int k = 0; k < 8; ++k) z[k] = (bf16)0.f;
        *(bf16x8*)&As[rr * 416 + cc] = z;
    }
    __syncthreads();

    int w = tid >> 6, lane = tid & 63, q = lane >> 4, r15 = lane & 15;
    f32x4 acc = {0.f, 0.f, 0.f, 0.f};
    const float* pB = Bw + (size_t)(w * 16 + r15) * 400;
#pragma unroll 4
    for (int kt = 0; kt < 13; ++kt) {
        int k0 = kt * 32 + q * 8;
        bf16x8 a = *(const bf16x8*)&As[r15 * 416 + k0];
        bf16x8 bb;
#pragma unroll
        for (int k = 0; k < 8; ++k) bb[k] = (bf16)0.f;
        if (k0 < 400) {
            f32x4 c0 = *(const f32x4*)(pB + k0);
            f32x4 c1 = *(const f32x4*)(pB + k0 + 4);
            bb[0] = (bf16)c0[0]; bb[1] = (bf16)c0[1]; bb[2] = (bf16)c0[2]; bb[3] = (bf16)c0[3];
            bb[4] = (bf16)c1[0]; bb[5] = (bf16)c1[1]; bb[6] = (bf16)c1[2]; bb[7] = (bf16)c1[3];
        }
        acc = __builtin_amdgcn_mfma_f32_16x16x32_bf16(a, bb, acc, 0, 0, 0);
    }
#pragma unroll
    for (int r = 0; r < 4; ++r) {
        int mm = m0 + q * 4 + r;
        int nn = w * 16 + r15;
        float v = fmaxf(acc[r] + bias[nn], 0.f);
        Cout[(size_t)mm * 64 + nn] = v;
    }
}

// ---------------- K8: BN2+relu+maxpool + concat + FC ----------------
__global__ __launch_bounds__(256) void k8_final(
    const bf16* __restrict__ g2out,
    const float* __restrict__ scale2, const float* __restrict__ shift2,
    const float* __restrict__ h2,
    const float* __restrict__ Wfc,
    const float* __restrict__ bfc,
    float* __restrict__ out)
{
    __shared__ float s2s[64], sh2s[64];
    int tid = threadIdx.x;
    if (tid < 64) { s2s[tid] = scale2[tid]; sh2s[tid] = shift2[tid]; }
    __syncthreads();
    int w = tid >> 6, lane = tid & 63;
    int b = blockIdx.x * 4 + w;
    int c = lane & 31, half = lane >> 5;
    const bf16* gb = g2out + (size_t)b * 2048;
    float mx = 0.f;
    for (int i = 0; i < 32; ++i) {
        int n = half * 32 + i;
        float v = (float)gb[n * 32 + c];
        float val = fmaf(s2s[n], v, sh2s[n]);
        mx = fmaxf(mx, val);
    }
    mx = fmaxf(mx, __shfl_xor(mx, 32));
    float h2v = h2[(size_t)b * 64 + lane];
#pragma unroll
    for (int o = 0; o < 2; ++o) {
        float t = h2v * Wfc[o * 96 + 32 + lane];
        if (half == 0) t += mx * Wfc[o * 96 + c];
#pragma unroll
        for (int off = 32; off > 0; off >>= 1) t += __shfl_xor(t, off);
        if (lane == 0) out[(size_t)b * 2 + o] = t + bfc[o];
    }
}

extern "C" void kernel_launch(void* const* d_in, const int* in_sizes, int n_in,
                              void* d_out, int out_size, void* d_ws, size_t ws_size,
                              hipStream_t stream)
{
    const float* x_fp   = (const float*)d_in[0];
    const float* x_node = (const float*)d_in[1];
    const int*   edge   = (const int*)d_in[2];
    const float* W1     = (const float*)d_in[3];
    const float* b1     = (const float*)d_in[4];
    const float* g1     = (const float*)d_in[5];
    const float* be1    = (const float*)d_in[6];
    const float* W2     = (const float*)d_in[7];
    const float* b2     = (const float*)d_in[8];
    const float* g2     = (const float*)d_in[9];
    const float* be2    = (const float*)d_in[10];
    const float* Wl1    = (const float*)d_in[11];
    const float* bl1    = (const float*)d_in[12];
    const float* Wl2    = (const float*)d_in[13];
    const float* bl2    = (const float*)d_in[14];
    const float* Wfc    = (const float*)d_in[15];
    const float* bfc    = (const float*)d_in[16];
    float* out = (float*)d_out;

    char* ws = (char*)d_ws;
    float* scale1  = (float*)(ws + 5632);
    float* shift1  = (float*)(ws + 5888);
    float* scale2  = (float*)(ws + 6144);
    float* shift2  = (float*)(ws + 6400);
    float* part1   = (float*)(ws + 8192);             // 65536 B
    float* part2   = (float*)(ws + 8192 + 65536);     // 65536 B
    bf16*  g1out   = (bf16*)(ws + 139264);            // 33554432 B (dead after k3 -> reused as part6)
    float* part6   = (float*)(ws + 139264);           // 26214400 B, overlays g1out
    bf16*  g2out   = (bf16*)(ws + 33693696ull);       // 16777216 B
    float* h2      = (float*)(ws + 53747712ull);      // 1048576 B
    // An + padded weight tables overlay the h2 region (dead before k7 writes h2).
    bf16*  an_hi   = (bf16*)(ws + 53747712ull);               // 8192 B
    bf16*  an_lo   = (bf16*)(ws + 53747712ull + 8192);        // 8192 B
    bf16*  wpad    = (bf16*)(ws + 53747712ull + 16384);       // 13312 B
    bf16*  w2pad   = (bf16*)(ws + 53747712ull + 32768);       // 4608 B
    bf16*  wl1b    = (bf16*)(ws + 58720256ull);               // 1835008 B: bf16 Wl1 [448][2048]

    k0_prep<<<dim3(64), dim3(256), 0, stream>>>(edge, W1, W2, Wl1, part1,
                                                an_hi, an_lo, wpad, w2pad, wl1b);
    k1_gcn1<<<dim3(1024), dim3(256), 0, stream>>>(x_node, b1, an_hi, an_lo, wpad, g1out, part1);
    k_bnstats<<<dim3(64), dim3(64), 0, stream>>>(part1, g1, be1, scale1, shift1,
                                                 1.f / (4096.f * 64.f));
    k3_gcn2<<<dim3(1024), dim3(256), 0, stream>>>(g1out, b2, scale1, shift1,
                                                  an_hi, an_lo, w2pad, g2out, part2);
    k_bnstats<<<dim3(64), dim3(64), 0, stream>>>(part2, g2, be2, scale2, shift2,
                                                 1.f / (4096.f * 32.f));
    // g1out is dead now; k6 writes split-K partials into its space
    k6_mlp1<<<dim3(64, 7, 4), dim3(256), 0, stream>>>(x_fp, wl1b, part6);
    k7_mlp2<<<dim3(256), dim3(256), 0, stream>>>(part6, bl1, Wl2, bl2, h2);
    k8_final<<<dim3(1024), dim3(256), 0, stream>>>(g2out, scale2, shift2, h2, Wfc, bfc, out);
}